// Round 2
// baseline (265.330 us; speedup 1.0000x reference)
//
#include <hip/hip_runtime.h>

// Fused: h = relu(X @ M + d), s0 = sum(h), where
//   M = W^T @ RW (20x20), d = b @ RW + 1 (20,)  -- precomputed by setup_kernel.
// Then n = #halvings of f32(s0) until <= 1; out = f32(s0) * 2^-n.
//
// Round-7 (vs round-6, 227.1 us): per-wave-private async staging.
//  * Each wave stages ONLY the 64 rows it consumes: 5 contiguous 1KB
//    global_load_lds (width=16) into its own 5KB LDS slice. No VGPR round
//    trip, no ds_write, and -- crucially -- NO __syncthreads in the main
//    loop: the only ordering needed is the wave's own s_waitcnt vmcnt(0).
//    Waves drift independently; other resident waves hide each drain.
//  * LDS layout is LINEAR (global_load_lds requirement). Row stride = 5
//    float4 = 80B (odd f4 stride) => ds_read_b128 at base 5*lane cycles
//    through all 8 bank-quads => conflict-free with ZERO padding.
//  * LDS 45KB -> 20.5KB: occupancy 3 -> up to 7 blocks/CU (28 waves).
//  * Persistent grid-stride loop (grid=2048) instead of 3907 one-shot
//    blocks: tail imbalance <= 1 chunk (~0.8us).
//  Mt/dvec stay uniform-CF s_load (scalar pipe) as in rounds 5-6; the
//  last-block ticket finalize is unchanged.

#define D 20
#define BLOCK 256
#define CHUNK_ROWS 256                  // 1 row / thread / chunk
#define CHUNK_F4 (CHUNK_ROWS * D / 4)   // 1280 float4 (20,480 B)
#define WAVE_F4 (CHUNK_F4 / 4)          // 320 float4 per wave slice
#define GRID 2048
#define WS_PARTIALS_BYTES 32768

#define GLOBAL_AS __attribute__((address_space(1)))
#define LDS_AS    __attribute__((address_space(3)))

// d_ws layout:
//   [0, 32768)            : double partials[4096] (one per block; 2048 used)
//   [32768, +1600)        : float Mt[400], Mt[j*D+k] = M[k][j]
//   [+1600, +1680)        : float dvec[20]
//   [+1680, +1684)        : unsigned counter (last-block ticket)

__device__ __forceinline__ void gload16(const float4* g, float4* l) {
    // async global->LDS, 16B/lane; LDS dest = wave-uniform base + lane*16
    __builtin_amdgcn_global_load_lds((const GLOBAL_AS void*)g,
                                     (LDS_AS void*)l, 16, 0, 0);
}

__global__ void setup_kernel(const float* __restrict__ W,
                             const float* __restrict__ b,
                             const float* __restrict__ RW,
                             float* __restrict__ Mt,
                             float* __restrict__ dvec,
                             unsigned* __restrict__ counter) {
    const int tid = threadIdx.x;
    if (tid == 0) *counter = 0u;  // ws is re-poisoned each iteration
    for (int idx = tid; idx < D * D; idx += blockDim.x) {
        const int j = idx / D, k = idx % D;
        float s = 0.0f;
        for (int i = 0; i < D; ++i)
            s = fmaf(W[i * D + k], RW[i * D + j], s);
        Mt[idx] = s;  // idx == j*D + k
    }
    if (tid < D) {
        float s = 1.0f;
        for (int i = 0; i < D; ++i)
            s = fmaf(b[i], RW[i * D + tid], s);
        dvec[tid] = s;
    }
}

__global__ void __launch_bounds__(BLOCK, 6)
fused_mlp_sum(const float* __restrict__ X,
              const float* __restrict__ Mt,
              const float* __restrict__ dvec,
              double* __restrict__ partials,
              unsigned* __restrict__ counter,
              float* __restrict__ out,
              int nrows) {
    __shared__ float4 lds4[CHUNK_F4];        // 20,480 B, linear, unpadded
    __shared__ float wave_sums[BLOCK / 64];
    __shared__ double dsum[BLOCK / 64];
    __shared__ int is_last;

    const int tid  = threadIdx.x;
    const int lane = tid & 63;
    const int wave = tid >> 6;
    const int bid  = blockIdx.x;
    const int G    = gridDim.x;
    const long long max_f4 = (((long long)nrows * D) >> 2) - 1;
    const int nchunks = (nrows + CHUNK_ROWS - 1) / CHUNK_ROWS;
    const float4* __restrict__ xg4 = (const float4*)X;
    float4* const wbuf = lds4 + wave * WAVE_F4;  // this wave's private slice

    float lsum = 0.0f;
    for (int c = bid; c < nchunks; c += G) {
        // ---- stage: 5x 1KB global_load_lds into own slice (coalesced) ----
        const long long base = (long long)c * CHUNK_F4 + wave * WAVE_F4;
#pragma unroll
        for (int i = 0; i < 5; ++i) {
            long long s = base + i * 64 + lane;
            s = (s <= max_f4) ? s : max_f4;   // clamp last partial chunk
            gload16(xg4 + s, wbuf + i * 64);
        }
        // wave-local completion wait; no block barrier anywhere in the loop
        asm volatile("s_waitcnt vmcnt(0)" ::: "memory");
        __builtin_amdgcn_sched_barrier(0);

        // ---- own row: 5x ds_read_b128 at stride 5 f4 (conflict-free) ----
        const float4* row = wbuf + 5 * lane;
        float x[D];
#pragma unroll
        for (int q = 0; q < 5; ++q) {
            const float4 v = row[q];
            x[4 * q + 0] = v.x; x[4 * q + 1] = v.y;
            x[4 * q + 2] = v.z; x[4 * q + 3] = v.w;
        }
        // ---- 20x20 FMA; Mt/dvec are uniform-CF -> s_load (scalar pipe) ----
        float rs = 0.0f;
#pragma unroll
        for (int j = 0; j < D; ++j) {
            float t = dvec[j];
#pragma unroll
            for (int k = 0; k < D; ++k)
                t = fmaf(x[k], Mt[j * D + k], t);
            rs += fmaxf(t, 0.0f);
        }
        lsum += ((long long)c * CHUNK_ROWS + tid < (long long)nrows) ? rs : 0.0f;
        // WAR on wbuf across iterations is within-wave only: x[] consumption
        // drains the ds_reads long before the next chunk's loads land.
    }

    // ---- block reduction -> one partial per block ----
#pragma unroll
    for (int off = 32; off > 0; off >>= 1)
        lsum += __shfl_down(lsum, off, 64);
    if (lane == 0) wave_sums[wave] = lsum;
    __syncthreads();

    if (tid == 0) {
        const float bs = wave_sums[0] + wave_sums[1] + wave_sums[2] + wave_sums[3];
        __hip_atomic_store(&partials[bid], (double)bs, __ATOMIC_RELEASE,
                           __HIP_MEMORY_SCOPE_AGENT);
        const unsigned t = __hip_atomic_fetch_add(counter, 1u, __ATOMIC_ACQ_REL,
                                                  __HIP_MEMORY_SCOPE_AGENT);
        is_last = (t == (unsigned)(G - 1));
    }
    __syncthreads();

    // ---- last block finalizes ----
    if (is_last) {
        double sd = 0.0;
        for (int i = tid; i < G; i += BLOCK)
            sd += __hip_atomic_load(&partials[i], __ATOMIC_RELAXED,
                                    __HIP_MEMORY_SCOPE_AGENT);
#pragma unroll
        for (int off = 32; off > 0; off >>= 1)
            sd += __shfl_down(sd, off, 64);
        if (lane == 0) dsum[wave] = sd;
        __syncthreads();
        if (tid == 0) {
            const double s0 = dsum[0] + dsum[1] + dsum[2] + dsum[3];
            float f = (float)s0;   // reference's s0 is f32
            while (f > 1.0f) f *= 0.5f;  // exact power-of-2 halvings
            out[0] = f;
        }
    }
}

extern "C" void kernel_launch(void* const* d_in, const int* in_sizes, int n_in,
                              void* d_out, int out_size, void* d_ws, size_t ws_size,
                              hipStream_t stream) {
    const float* X  = (const float*)d_in[0];
    const float* W  = (const float*)d_in[1];
    const float* b  = (const float*)d_in[2];
    const float* RW = (const float*)d_in[3];
    float* out = (float*)d_out;

    double* partials = (double*)d_ws;
    float*  Mt = (float*)((char*)d_ws + WS_PARTIALS_BYTES);
    float*  dv = Mt + D * D;
    unsigned* counter = (unsigned*)((char*)d_ws + WS_PARTIALS_BYTES + 1600 + 80);

    const int nrows = in_sizes[0] / (D * 4);  // 2,000,000

    setup_kernel<<<1, 256, 0, stream>>>(W, b, RW, Mt, dv, counter);

    fused_mlp_sum<<<GRID, BLOCK, 0, stream>>>(X, Mt, dv, partials, counter,
                                              out, nrows);
}

// Round 3
// 229.024 us; speedup vs baseline: 1.1585x; 1.1585x over previous
//
#include <hip/hip_runtime.h>

// Fused: h = relu(X @ M + d), s0 = sum(h), where
//   M = W^T @ RW (20x20), d = b @ RW + 1 (20,)  -- precomputed by setup_kernel.
// Then n = #halvings of f32(s0) until <= 1; out = f32(s0) * 2^-n.
//
// Round-8 (recovery from round-7 regression, 265 us):
//  Round-7's per-wave global_load_lds + vmcnt(0) serial round-trips were
//  latency-bound (VALUBusy 5%, HBM 2%): LDS-DMA caps per-wave MLP at the
//  queue depth and the explicit waits defeat compiler pipelining. REVERT to
//  the verified round-5/6 structure:
//   * Direct per-lane float4 row loads (10 independent loads in flight per
//     thread; compiler slides the 800-cycle FMA chain under them).
//   * UNIFORM control flow: tail lanes clamp the row base with a select and
//     mask their sum -- the backend scalarizes Mt/dvec to s_load (SGPR
//     operands, scalar pipe, sK$), zero VGPR cost for the matrix.
//   * Merged finalize via last-block ticket (saves the extra launch, ~4us,
//     verified in round-6).
//  Delta vs round-6: NO LDS staging at all (~48B LDS). Occupancy is no
//  longer LDS-capped (was 3 blocks/CU at 45KB); no barrier anywhere in the
//  main body, so waves never couple on a per-tile load drain.

#define D 20
#define BLOCK 256
#define RPT 2  // rows per thread
#define RPB (BLOCK * RPT)
#define WS_PARTIALS_BYTES 32768

// d_ws layout:
//   [0, 32768)            : double partials[4096] (one per block; 3907 used)
//   [32768, +1600)        : float Mt[400], Mt[j*D+k] = M[k][j]
//   [+1600, +1680)        : float dvec[20]
//   [+1680, +1684)        : unsigned counter (last-block ticket)

__global__ void setup_kernel(const float* __restrict__ W,
                             const float* __restrict__ b,
                             const float* __restrict__ RW,
                             float* __restrict__ Mt,
                             float* __restrict__ dvec,
                             unsigned* __restrict__ counter) {
    const int tid = threadIdx.x;
    if (tid == 0) *counter = 0u;  // ws is re-poisoned each iteration
    for (int idx = tid; idx < D * D; idx += blockDim.x) {
        const int j = idx / D, k = idx % D;
        float s = 0.0f;
        for (int i = 0; i < D; ++i)
            s = fmaf(W[i * D + k], RW[i * D + j], s);
        Mt[idx] = s;  // idx == j*D + k
    }
    if (tid < D) {
        float s = 1.0f;
        for (int i = 0; i < D; ++i)
            s = fmaf(b[i], RW[i * D + tid], s);
        dvec[tid] = s;
    }
}

__global__ void __launch_bounds__(BLOCK)
fused_mlp_sum(const float* __restrict__ X,
              const float* __restrict__ Mt,
              const float* __restrict__ dvec,
              double* __restrict__ partials,
              unsigned* __restrict__ counter,
              float* __restrict__ out,
              int nrows) {
    __shared__ float wave_sums[BLOCK / 64];
    __shared__ double dsum[BLOCK / 64];
    __shared__ int is_last;

    const int tid  = threadIdx.x;
    const int lane = tid & 63;
    const int wave = tid >> 6;
    const long long t = (long long)blockIdx.x * BLOCK + tid;
    const long long row0 = t * RPT;
    const bool valid = row0 < (long long)nrows;
    // Clamp instead of branch: control flow stays UNIFORM so the backend
    // scalarizes the Mt/dvec loads (s_load). Clamped lanes read real memory
    // (in-bounds) and are masked out of the sum below.
    const long long rbase = valid ? row0 : (long long)nrows - RPT;
    const float* xp = X + rbase * D;

    // 10 independent float4 loads per thread -- all issued before first use;
    // the compiler interleaves the FMA chain under their latency.
    float x0[D], x1[D];
#pragma unroll
    for (int q = 0; q < 5; ++q) {
        float4 v = ((const float4*)xp)[q];
        x0[4 * q + 0] = v.x; x0[4 * q + 1] = v.y;
        x0[4 * q + 2] = v.z; x0[4 * q + 3] = v.w;
        float4 u = ((const float4*)(xp + D))[q];
        x1[4 * q + 0] = u.x; x1[4 * q + 1] = u.y;
        x1[4 * q + 2] = u.z; x1[4 * q + 3] = u.w;
    }

    float lsum = 0.0f;
#pragma unroll
    for (int j = 0; j < D; ++j) {
        float t0 = dvec[j];   // uniform addr + uniform CF -> s_load (SGPR)
        float t1 = t0;
#pragma unroll
        for (int k = 0; k < D; ++k) {
            const float m = Mt[j * D + k];  // s_load, scalar pipe
            t0 = fmaf(x0[k], m, t0);        // v_fma with SGPR src
            t1 = fmaf(x1[k], m, t1);
        }
        lsum += fmaxf(t0, 0.0f) + fmaxf(t1, 0.0f);
    }
    lsum = valid ? lsum : 0.0f;  // mask clamped tail lanes

    // ---- Block reduction -> one partial per block (no atomic contention) ----
#pragma unroll
    for (int off = 32; off > 0; off >>= 1)
        lsum += __shfl_down(lsum, off, 64);
    if (lane == 0) wave_sums[wave] = lsum;
    __syncthreads();

    if (tid == 0) {
        const float bs = wave_sums[0] + wave_sums[1] + wave_sums[2] + wave_sums[3];
        // Release store: must be visible to the last block on another XCD.
        __hip_atomic_store(&partials[blockIdx.x], (double)bs, __ATOMIC_RELEASE,
                           __HIP_MEMORY_SCOPE_AGENT);
        const unsigned tk = __hip_atomic_fetch_add(counter, 1u, __ATOMIC_ACQ_REL,
                                                   __HIP_MEMORY_SCOPE_AGENT);
        is_last = (tk == gridDim.x - 1);
    }
    __syncthreads();

    // ---- Last block finalizes (replaces a separate finalize launch) ----
    if (is_last) {
        double sd = 0.0;
        for (int i = tid; i < (int)gridDim.x; i += BLOCK)
            sd += __hip_atomic_load(&partials[i], __ATOMIC_RELAXED,
                                    __HIP_MEMORY_SCOPE_AGENT);
#pragma unroll
        for (int off = 32; off > 0; off >>= 1)
            sd += __shfl_down(sd, off, 64);
        if (lane == 0) dsum[wave] = sd;
        __syncthreads();
        if (tid == 0) {
            const double s0 = dsum[0] + dsum[1] + dsum[2] + dsum[3];
            float f = (float)s0;   // reference's s0 is f32
            while (f > 1.0f) f *= 0.5f;  // exact power-of-2 halvings
            out[0] = f;
        }
    }
}

extern "C" void kernel_launch(void* const* d_in, const int* in_sizes, int n_in,
                              void* d_out, int out_size, void* d_ws, size_t ws_size,
                              hipStream_t stream) {
    const float* X  = (const float*)d_in[0];
    const float* W  = (const float*)d_in[1];
    const float* b  = (const float*)d_in[2];
    const float* RW = (const float*)d_in[3];
    float* out = (float*)d_out;

    double* partials = (double*)d_ws;
    float*  Mt = (float*)((char*)d_ws + WS_PARTIALS_BYTES);
    float*  dv = Mt + D * D;
    unsigned* counter = (unsigned*)((char*)d_ws + WS_PARTIALS_BYTES + 1600 + 80);

    const int nrows = in_sizes[0] / (D * 4);  // 2,000,000

    setup_kernel<<<1, 256, 0, stream>>>(W, b, RW, Mt, dv, counter);

    const long long nthreads = ((long long)nrows + RPT - 1) / RPT;  // 1,000,000
    const int blocks = (int)((nthreads + BLOCK - 1) / BLOCK);       // 3907
    fused_mlp_sum<<<blocks, BLOCK, 0, stream>>>(X, Mt, dv, partials, counter,
                                                out, nrows);
}